// Round 8
// baseline (670.856 us; speedup 1.0000x reference)
//
#include <hip/hip_runtime.h>
#include <hip/hip_fp16.h>
#include <math.h>

#define NN 100000
#define EE 1600000
#define ET 1700000   // EE + NN self loops
#define NEG 0.2f
#define NCH 98       // ceil(NN/1024)
#define PCH 8192     // edges per partition block
#define NPB 208      // ceil(ET/PCH)
#define BCAP 24576   // bucket capacity (mean ~17.4K, std ~132 -> 54 sigma)

typedef _Float16 half8_t __attribute__((ext_vector_type(8)));
typedef float f32x4 __attribute__((ext_vector_type(4)));

// ---------------- ws layout (bytes) ----------------
static constexpr size_t alignup(size_t x) { return (x + 255) & ~(size_t)255; }
static constexpr size_t OFF_H1H  = 0;                                    // N*64 fp16
static constexpr size_t OFF_HELU = alignup(OFF_H1H  + (size_t)NN*64*2);  // N*64 fp16
static constexpr size_t OFF_AS1H = alignup(OFF_HELU + (size_t)NN*64*2);  // N*8 fp16
static constexpr size_t OFF_AD1  = alignup(OFF_AS1H + (size_t)NN*8*2);   // N*8 f32
static constexpr size_t OFF_AS2H = alignup(OFF_AD1  + (size_t)NN*8*4);   // N*8 fp16
static constexpr size_t OFF_AD2  = alignup(OFF_AS2H + (size_t)NN*8*2);   // N*8 f32
static constexpr size_t OFF_WSD2 = alignup(OFF_AD2  + (size_t)NN*8*4);   // 64*16 f32
static constexpr size_t OFF_W2T  = alignup(OFF_WSD2 + 64*16*4);          // 64*512 fp16
static constexpr size_t OFF_W1T  = alignup(OFF_W2T  + 64*512*2);         // 64*256 fp16
static constexpr size_t OFF_HIST = alignup(OFF_W1T  + 64*256*2);         // N int
static constexpr size_t OFF_BCNT = alignup(OFF_HIST + (size_t)NN*4);     // 128 int
static constexpr size_t OFF_INC  = alignup(OFF_BCNT + 128*4);
static constexpr size_t OFF_PART = alignup(OFF_INC  + (size_t)NN*4);
static constexpr size_t OFF_OFFS = alignup(OFF_PART + 128*4);
static constexpr size_t OFF_RP   = alignup(OFF_OFFS + 128*4);
static constexpr size_t OFF_CUR  = alignup(OFF_RP   + (size_t)(NN+1)*4);
static constexpr size_t OFF_SRC  = alignup(OFF_CUR  + (size_t)NN*4);     // ET int
static constexpr size_t OFF_BKT  = alignup(OFF_SRC  + (size_t)ET*4);     // 128*BCAP u64

__device__ inline void unpack8(float4 raw, float* g) {
  __half2* hp = (__half2*)&raw;
  float2 a = __half22float2(hp[0]); g[0] = a.x; g[1] = a.y;
  float2 b = __half22float2(hp[1]); g[2] = b.x; g[3] = b.y;
  float2 c = __half22float2(hp[2]); g[4] = c.x; g[5] = c.y;
  float2 d = __half22float2(hp[3]); g[6] = d.x; g[7] = d.y;
}

// ---------------- W1t[f][k] = fp16(W1[k][f]) ----------------
__global__ void k_w1t(const float* __restrict__ W1, _Float16* __restrict__ W1t) {
  int t = blockIdx.x * 256 + threadIdx.x;  // 16384 = 64*256
  if (t >= 64 * 256) return;
  int f = t >> 8, k = t & 255;
  W1t[t] = (_Float16)W1[k * 64 + f];
}

// ---------------- GEMM1 via MFMA: h1h = fp16(x[N,256] @ W1t^T) --------------
__global__ __launch_bounds__(256) void k_gemm1m(const float* __restrict__ x,
                                                const _Float16* __restrict__ W1t,
                                                __half* __restrict__ h1h) {
  const int lane = threadIdx.x & 63;
  const int wv = threadIdx.x >> 6;
  const int m16 = lane & 15;
  const int q = lane >> 4;
  const int row = blockIdx.x * 64 + wv * 16 + m16;
  const bool rok = row < NN;
  const float* xr = x + (size_t)row * 256 + q * 8;
  f32x4 c0 = {0.f, 0.f, 0.f, 0.f}, c1 = c0, c2 = c0, c3 = c0;
#pragma unroll
  for (int k0 = 0; k0 < 256; k0 += 32) {
    half8_t a;
    if (rok) {
      float4 xa = ((const float4*)(xr + k0))[0];
      float4 xb = ((const float4*)(xr + k0))[1];
      a[0] = (_Float16)xa.x; a[1] = (_Float16)xa.y;
      a[2] = (_Float16)xa.z; a[3] = (_Float16)xa.w;
      a[4] = (_Float16)xb.x; a[5] = (_Float16)xb.y;
      a[6] = (_Float16)xb.z; a[7] = (_Float16)xb.w;
    } else {
#pragma unroll
      for (int i = 0; i < 8; i++) a[i] = (_Float16)0.f;
    }
    half8_t b0 = *((const half8_t*)(W1t + (size_t)(0 * 16 + m16) * 256 + k0 + q * 8));
    half8_t b1 = *((const half8_t*)(W1t + (size_t)(1 * 16 + m16) * 256 + k0 + q * 8));
    half8_t b2 = *((const half8_t*)(W1t + (size_t)(2 * 16 + m16) * 256 + k0 + q * 8));
    half8_t b3 = *((const half8_t*)(W1t + (size_t)(3 * 16 + m16) * 256 + k0 + q * 8));
    c0 = __builtin_amdgcn_mfma_f32_16x16x32_f16(a, b0, c0, 0, 0, 0);
    c1 = __builtin_amdgcn_mfma_f32_16x16x32_f16(a, b1, c1, 0, 0, 0);
    c2 = __builtin_amdgcn_mfma_f32_16x16x32_f16(a, b2, c2, 0, 0, 0);
    c3 = __builtin_amdgcn_mfma_f32_16x16x32_f16(a, b3, c3, 0, 0, 0);
  }
#pragma unroll
  for (int r = 0; r < 4; r++) {
    int orow = blockIdx.x * 64 + wv * 16 + q * 4 + r;
    if (orow >= NN) continue;
    __half* op = h1h + (size_t)orow * 64;
    op[0 * 16 + m16] = __float2half(c0[r]);
    op[1 * 16 + m16] = __float2half(c1[r]);
    op[2 * 16 + m16] = __float2half(c2[r]);
    op[3 * 16 + m16] = __float2half(c3[r]);
  }
}

// ---------------- attention logits from h1h ----------------
__global__ void k_alpha1h(const __half* __restrict__ h1h, const float* __restrict__ a_src1,
                          const float* __restrict__ a_dst1, __half* __restrict__ as1h,
                          float* __restrict__ ad1) {
  int g = blockIdx.x * 256 + threadIdx.x;
  if (g >= NN * 8) return;
  int n = g >> 3, h = g & 7;
  float4 raw = *((const float4*)&h1h[(size_t)n * 64 + h * 8]);
  float v[8];
  unpack8(raw, v);
  float s = 0.f, d = 0.f;
#pragma unroll
  for (int f = 0; f < 8; f++) {
    s += v[f] * a_src1[h * 8 + f];
    d += v[f] * a_dst1[h * 8 + f];
  }
  as1h[g] = __float2half(s);
  ad1[g] = d;
}

// ---------------- wsd2[k*16+j]: j<8 -> W2-proj of a_src2, else a_dst2 --------
__global__ void k_w2proj(const float* __restrict__ W2, const float* __restrict__ a_src2,
                         const float* __restrict__ a_dst2, float* __restrict__ wsd2) {
  int t = threadIdx.x;  // 1024 threads: t = k*16+j
  int k = t >> 4, j = t & 15, h = j & 7;
  const float* av = (j < 8) ? a_src2 : a_dst2;
  float s = 0.f;
  for (int f = 0; f < 64; f++) s += W2[k * 512 + h * 64 + f] * av[h * 64 + f];
  wsd2[t] = s;
}

// ---------------- W2t[f][h*64+kk] = fp16(W2[kk][h*64+f]) --------------------
__global__ void k_w2t(const float* __restrict__ W2, _Float16* __restrict__ W2t) {
  int t = blockIdx.x * 256 + threadIdx.x;  // 32768 = 64*512
  if (t >= 64 * 512) return;
  int f = t >> 9, k = t & 511;
  int h = k >> 6, kk = k & 63;
  W2t[t] = (_Float16)W2[kk * 512 + h * 64 + f];
}

// ---------------- pass A: partition into fixed-cap dst-buckets + per-dst hist
__global__ __launch_bounds__(256) void k_part(const int* __restrict__ edge,
                                              int* __restrict__ hist,
                                              int* __restrict__ bcnt,
                                              unsigned long long* __restrict__ bkt) {
  __shared__ int lcnt[128];
  __shared__ int lbase[128];
  __shared__ int loff[128];
  const int t = threadIdx.x;
  const int e0 = blockIdx.x * PCH;
  if (t < 128) { lcnt[t] = 0; loff[t] = 0; }
  __syncthreads();
  for (int i = t; i < PCH; i += 256) {
    int e = e0 + i;
    if (e >= ET) break;
    int d = (e < EE) ? edge[EE + e] : (e - EE);
    atomicAdd(&hist[d], 1);
    atomicAdd(&lcnt[d >> 10], 1);
  }
  __syncthreads();
  if (t < 128 && lcnt[t] > 0) lbase[t] = atomicAdd(&bcnt[t], lcnt[t]);
  __syncthreads();
  for (int i = t; i < PCH; i += 256) {
    int e = e0 + i;
    if (e >= ET) break;
    int s, d;
    if (e < EE) { s = edge[e]; d = edge[EE + e]; } else { s = e - EE; d = s; }
    int b = d >> 10;
    int off = lbase[b] + atomicAdd(&loff[b], 1);
    if (off < BCAP)
      bkt[(size_t)b * BCAP + off] = ((unsigned long long)d << 32) | (unsigned)s;
  }
}

// ---------------- prefix-scan over hist -> rp (CSR row pointers) ------------
__global__ void k_scan_a(const int* __restrict__ hist, int* __restrict__ inc,
                         int* __restrict__ part) {
  __shared__ int sm[1024];
  int t = threadIdx.x, c = blockIdx.x;
  int i = c * 1024 + t;
  int v = (i < NN) ? hist[i] : 0;
  sm[t] = v;
  for (int off = 1; off < 1024; off <<= 1) {
    __syncthreads();
    int a = (t >= off) ? sm[t - off] : 0;
    __syncthreads();
    sm[t] += a;
  }
  if (i < NN) inc[i] = sm[t];
  if (t == 1023) part[c] = sm[1023];
}

__global__ void k_scan_b(const int* __restrict__ part, int* __restrict__ offs) {
  int t = threadIdx.x;
  if (t >= 128) return;
  int run = 0;
  for (int c = 0; c < NCH; c++)
    if (c < t) run += part[c];
  if (t < NCH) offs[t] = run;
}

__global__ void k_scan_c(const int* __restrict__ hist, const int* __restrict__ inc,
                         const int* __restrict__ offs, int* __restrict__ rp,
                         int* __restrict__ cur) {
  int t = threadIdx.x, c = blockIdx.x;
  int i = c * 1024 + t;
  if (i < NN) {
    int r = inc[i] - hist[i] + offs[c];
    rp[i] = r;
    cur[i] = r;
  }
  if (i == 0) rp[NN] = ET;
}

// ---------------- pass B: finalize per-dst scatter (writes stay L2-local) ---
__global__ void k_scatfin(const unsigned long long* __restrict__ bkt,
                          const int* __restrict__ bcnt,
                          int* __restrict__ cur, int* __restrict__ ssrc) {
  int b = blockIdx.y;
  int i = blockIdx.x * 256 + threadIdx.x;
  if (i >= bcnt[b]) return;
  unsigned long long v = bkt[(size_t)b * BCAP + i];
  int d = (int)(v >> 32);
  int s = (int)(v & 0xffffffffu);
  int pos = atomicAdd(&cur[d], 1);
  ssrc[pos] = s;
}

// ---------------- layer-1 aggregation (fp16 gathers, 8 edges/instr) ---------
__global__ __launch_bounds__(256) void k_aggB1(
    const __half* __restrict__ h1h, const __half* __restrict__ as1h,
    const float* __restrict__ ad1, const float* __restrict__ b1,
    const int* __restrict__ rp, const int* __restrict__ ssrc,
    const float* __restrict__ wsd2,
    __half* __restrict__ heluh, __half* __restrict__ as2h, float* __restrict__ ad2) {
  __shared__ float lds_p[4][512];
  __shared__ int   lds_s[4][64];
  __shared__ float lds_v[4][64];
  const int lane = threadIdx.x & 63;
  const int wv = threadIdx.x >> 6;
  const int d = blockIdx.x * 4 + wv;
  if (d >= NN) return;
  const int eg = lane >> 3;        // edge subgroup 0..7
  const int fl = lane & 7;         // 8-feature slice == head (phase B)
  float4 a0 = ((const float4*)ad1)[d * 2];
  float4 a1 = ((const float4*)ad1)[d * 2 + 1];
  const float adv[8] = {a0.x, a0.y, a0.z, a0.w, a1.x, a1.y, a1.z, a1.w};
  const int r0 = rp[d], r1 = rp[d + 1];
  float acc[8];
#pragma unroll
  for (int k = 0; k < 8; k++) acc[k] = 0.f;
  float lsum = 0.f;
  for (int base = r0; base < r1; base += 64) {
    int idx = base + lane;
    float p[8];
    int s = 0;
    if (idx < r1) {
      s = ssrc[idx];
      float4 raw = *((const float4*)&as1h[s * 8]);
      float ev[8];
      unpack8(raw, ev);
#pragma unroll
      for (int h = 0; h < 8; h++) {
        float e = ev[h] + adv[h];
        e = e > 0.f ? e : NEG * e;
        p[h] = __expf(e);
      }
    } else {
#pragma unroll
      for (int h = 0; h < 8; h++) p[h] = 0.f;
    }
    lds_s[wv][lane] = s;
    *((float4*)&lds_p[wv][lane * 8]) = make_float4(p[0], p[1], p[2], p[3]);
    *((float4*)&lds_p[wv][lane * 8 + 4]) = make_float4(p[4], p[5], p[6], p[7]);
    int nc = (min(64, r1 - base) + 7) >> 3;
#pragma unroll 2
    for (int j = 0; j < nc; j++) {
      int e = j * 8 + eg;
      int sj = lds_s[wv][e];
      float w = lds_p[wv][e * 8 + fl];
      float4 raw = *((const float4*)&h1h[(size_t)sj * 64 + fl * 8]);
      float g[8];
      unpack8(raw, g);
      lsum += w;
#pragma unroll
      for (int k = 0; k < 8; k++) acc[k] += w * g[k];
    }
  }
  // reduce across 8 edge subgroups (lane bits 3,4,5)
#pragma unroll
  for (int off = 8; off <= 32; off <<= 1) {
#pragma unroll
    for (int k = 0; k < 8; k++) acc[k] += __shfl_xor(acc[k], off, 64);
    lsum += __shfl_xor(lsum, off, 64);
  }
  if (lane < 8) {
#pragma unroll
    for (int k = 0; k < 8; k++) lds_v[wv][lane * 8 + k] = acc[k];
    lds_p[wv][lane] = lsum;   // l[head=lane]
  }
  float accs = lds_v[wv][lane];
  float lv = lds_p[wv][lane >> 3];
  float val = accs / lv + b1[lane];
  val = val > 0.f ? val : __expf(val) - 1.f;  // ELU
  heluh[(size_t)d * 64 + lane] = __float2half(val);
  // layer-2 logits: 4 groups of 16 features x 16 outputs (8 src + 8 dst)
  lds_v[wv][lane] = val;
  int g = lane >> 4, j = lane & 15;
  float dot = 0.f;
#pragma unroll
  for (int f = 0; f < 16; f++) dot += lds_v[wv][g * 16 + f] * wsd2[(g * 16 + f) * 16 + j];
  dot += __shfl_xor(dot, 16, 64);
  dot += __shfl_xor(dot, 32, 64);
  if (lane < 16) {
    if (j < 8) as2h[d * 8 + j] = __float2half(dot);
    else       ad2[d * 8 + (j & 7)] = dot;
  }
}

// ---------------- layer-2 aggregation + fused MFMA output GEMM --------------
// Aggregates per-dst 512-vec (8 heads x 64 feat) in registers, stages scaled
// result in LDS (row pad 520 -> 2-way bank alias, free), then each of the 4
// waves computes one 16-col tile of agg[4x512] @ W2t via mfma, writing out
// f32 directly. Eliminates the aggh HBM round-trip (100MB w + 102MB r).
// NOTE: grid is exactly NN/4 blocks (NN%4==0) -> no early-exit divergence.
__global__ __launch_bounds__(256) void k_aggC2(
    const __half* __restrict__ heluh, const __half* __restrict__ as2h,
    const float* __restrict__ ad2, const int* __restrict__ rp,
    const int* __restrict__ ssrc, const _Float16* __restrict__ W2t,
    const float* __restrict__ b2, float* __restrict__ out) {
  __shared__ float lds_p[4][512];
  __shared__ int   lds_s[4][64];
  __shared__ _Float16 lds_a[4][520];   // 520 pad: bank = 4*(row)+... 2-way only
  const int lane = threadIdx.x & 63;
  const int wv = threadIdx.x >> 6;
  const int d = blockIdx.x * 4 + wv;
  const int eg = lane >> 4;        // edge subgroup 0..3
  const int fl = lane & 15;        // 4-feature slice
  float4 a0 = ((const float4*)ad2)[d * 2];
  float4 a1 = ((const float4*)ad2)[d * 2 + 1];
  const float adv[8] = {a0.x, a0.y, a0.z, a0.w, a1.x, a1.y, a1.z, a1.w};
  const int r0 = rp[d], r1 = rp[d + 1];
  float l8[8];
  float acc[8][4];
#pragma unroll
  for (int h = 0; h < 8; h++) {
    l8[h] = 0.f;
#pragma unroll
    for (int k = 0; k < 4; k++) acc[h][k] = 0.f;
  }
  for (int base = r0; base < r1; base += 64) {
    int idx = base + lane;
    float p[8];
    int s = 0;
    if (idx < r1) {
      s = ssrc[idx];
      float4 raw = *((const float4*)&as2h[s * 8]);
      float ev[8];
      unpack8(raw, ev);
#pragma unroll
      for (int h = 0; h < 8; h++) {
        float e = ev[h] + adv[h];
        e = e > 0.f ? e : NEG * e;
        p[h] = __expf(e);
      }
    } else {
#pragma unroll
      for (int h = 0; h < 8; h++) p[h] = 0.f;
    }
    lds_s[wv][lane] = s;
    *((float4*)&lds_p[wv][lane * 8]) = make_float4(p[0], p[1], p[2], p[3]);
    *((float4*)&lds_p[wv][lane * 8 + 4]) = make_float4(p[4], p[5], p[6], p[7]);
    int nc = (min(64, r1 - base) + 3) >> 2;
#pragma unroll 2
    for (int j = 0; j < nc; j++) {
      int e = j * 4 + eg;
      int sj = lds_s[wv][e];
      float2 raw = *((const float2*)&heluh[(size_t)sj * 64 + fl * 4]);
      __half2* hp = (__half2*)&raw;
      float2 ga = __half22float2(hp[0]);
      float2 gb = __half22float2(hp[1]);
      float g[4] = {ga.x, ga.y, gb.x, gb.y};
      float4 w0 = *((const float4*)&lds_p[wv][e * 8]);
      float4 w1 = *((const float4*)&lds_p[wv][e * 8 + 4]);
      float w[8] = {w0.x, w0.y, w0.z, w0.w, w1.x, w1.y, w1.z, w1.w};
#pragma unroll
      for (int h = 0; h < 8; h++) {
        l8[h] += w[h];
#pragma unroll
        for (int k = 0; k < 4; k++) acc[h][k] += w[h] * g[k];
      }
    }
  }
  // reduce across 4 edge subgroups (lane bits 4,5)
#pragma unroll
  for (int off = 16; off <= 32; off <<= 1) {
#pragma unroll
    for (int h = 0; h < 8; h++) {
      l8[h] += __shfl_xor(l8[h], off, 64);
#pragma unroll
      for (int k = 0; k < 4; k++) acc[h][k] += __shfl_xor(acc[h][k], off, 64);
    }
  }
  // stage scaled agg vector to LDS (fp16)
  if (lane < 16) {
#pragma unroll
    for (int h = 0; h < 8; h++) {
      float rl = 1.0f / l8[h];
      __half2 p0 = __floats2half2_rn(acc[h][0] * rl, acc[h][1] * rl);
      __half2 p1 = __floats2half2_rn(acc[h][2] * rl, acc[h][3] * rl);
      *((__half2*)&lds_a[wv][h * 64 + fl * 4])     = p0;
      *((__half2*)&lds_a[wv][h * 64 + fl * 4 + 2]) = p1;
    }
  }
  __syncthreads();
  // fused GEMM: wave wv computes cols [wv*16, wv*16+16) for the block's 4 dsts
  const int m16 = lane & 15;
  const int q = lane >> 4;
  const _Float16* brow = W2t + (size_t)(wv * 16 + m16) * 512 + q * 8;
  half8_t zero8;
#pragma unroll
  for (int i = 0; i < 8; i++) zero8[i] = (_Float16)0.f;
  f32x4 c = {0.f, 0.f, 0.f, 0.f};
#pragma unroll
  for (int k0 = 0; k0 < 512; k0 += 32) {
    half8_t a = (m16 < 4) ? *((const half8_t*)&lds_a[m16][k0 + q * 8]) : zero8;
    half8_t b = *((const half8_t*)(brow + k0));
    c = __builtin_amdgcn_mfma_f32_16x16x32_f16(a, b, c, 0, 0, 0);
  }
  if (q == 0) {
    float bias = b2[wv * 16 + m16];
#pragma unroll
    for (int r = 0; r < 4; r++) {
      int dd = blockIdx.x * 4 + r;
      out[(size_t)dd * 64 + wv * 16 + m16] = 0.125f * c[r] + bias;
    }
  }
}

extern "C" void kernel_launch(void* const* d_in, const int* in_sizes, int n_in,
                              void* d_out, int out_size, void* d_ws, size_t ws_size,
                              hipStream_t stream) {
  const float* x      = (const float*)d_in[0];
  const float* W1     = (const float*)d_in[1];
  const float* a_src1 = (const float*)d_in[2];
  const float* a_dst1 = (const float*)d_in[3];
  const float* b1     = (const float*)d_in[4];
  const float* W2     = (const float*)d_in[5];
  const float* a_src2 = (const float*)d_in[6];
  const float* a_dst2 = (const float*)d_in[7];
  const float* b2     = (const float*)d_in[8];
  const int*   edge   = (const int*)d_in[9];

  char* ws = (char*)d_ws;
  __half* h1h   = (__half*)(ws + OFF_H1H);
  __half* heluh = (__half*)(ws + OFF_HELU);
  __half* as1h  = (__half*)(ws + OFF_AS1H);
  float*  ad1   = (float*)(ws + OFF_AD1);
  __half* as2h  = (__half*)(ws + OFF_AS2H);
  float*  ad2   = (float*)(ws + OFF_AD2);
  float*  wsd2  = (float*)(ws + OFF_WSD2);
  _Float16* W2t = (_Float16*)(ws + OFF_W2T);
  _Float16* W1t = (_Float16*)(ws + OFF_W1T);
  int* hist   = (int*)(ws + OFF_HIST);
  int* bcnt   = (int*)(ws + OFF_BCNT);
  int* inc    = (int*)(ws + OFF_INC);
  int* part   = (int*)(ws + OFF_PART);
  int* offs   = (int*)(ws + OFF_OFFS);
  int* rp     = (int*)(ws + OFF_RP);
  int* cur    = (int*)(ws + OFF_CUR);
  int* ssrc   = (int*)(ws + OFF_SRC);
  unsigned long long* bkt = (unsigned long long*)(ws + OFF_BKT);
  float* out  = (float*)d_out;

  hipMemsetAsync(hist, 0, (size_t)NN * 4, stream);
  hipMemsetAsync(bcnt, 0, 128 * 4, stream);

  k_w1t<<<64, 256, 0, stream>>>(W1, W1t);
  k_gemm1m<<<(NN + 63) / 64, 256, 0, stream>>>(x, W1t, h1h);
  k_alpha1h<<<(NN * 8 + 255) / 256, 256, 0, stream>>>(h1h, a_src1, a_dst1, as1h, ad1);
  k_w2proj<<<1, 1024, 0, stream>>>(W2, a_src2, a_dst2, wsd2);
  k_w2t<<<128, 256, 0, stream>>>(W2, W2t);
  k_part<<<NPB, 256, 0, stream>>>(edge, hist, bcnt, bkt);
  k_scan_a<<<NCH, 1024, 0, stream>>>(hist, inc, part);
  k_scan_b<<<1, 128, 0, stream>>>(part, offs);
  k_scan_c<<<NCH, 1024, 0, stream>>>(hist, inc, offs, rp, cur);
  {
    dim3 g(BCAP / 256, 128);
    k_scatfin<<<g, 256, 0, stream>>>(bkt, bcnt, cur, ssrc);
  }
  k_aggB1<<<(NN + 3) / 4, 256, 0, stream>>>(h1h, as1h, ad1, b1, rp, ssrc, wsd2, heluh, as2h, ad2);
  k_aggC2<<<NN / 4, 256, 0, stream>>>(heluh, as2h, ad2, rp, ssrc, W2t, b2, out);
}